// Round 11
// baseline (1809.045 us; speedup 1.0000x reference)
//
#include <hip/hip_runtime.h>
#include <hip/hip_bf16.h>

#define B_  64
#define T_  512
#define V_  512
#define E_  128
#define D_  256
#define D2_ 512

#define NPQ    4096          // 512 t * 8 n-tiles
#define NEN    8704          // 136 pi * 64 b
#define NITEMS (NPQ + NEN)

typedef unsigned short u16;
typedef unsigned int   u32;
typedef short s16x8 __attribute__((ext_vector_type(8)));
typedef _Float16 f16x8 __attribute__((ext_vector_type(8)));
typedef float f32x4 __attribute__((ext_vector_type(4)));
typedef unsigned short u16x2 __attribute__((ext_vector_type(2)));
typedef unsigned short u16x4 __attribute__((ext_vector_type(4)));

__device__ __forceinline__ float bf2f(u16 u){
    union { u32 i; float f; } c; c.i = ((u32)u) << 16; return c.f;
}
__device__ __forceinline__ u16 f2bf(float f){
    union { float f; u32 i; } c; c.f = f;
    u32 u = c.i;
    return (u16)((u + 0x7fffu + ((u >> 16) & 1u)) >> 16);
}
__device__ __forceinline__ u16 f2h(float f){
    union { _Float16 h; u16 u; } c; c.h = (_Float16)f; return c.u;
}
// tanh for bounded args (|x| <~ 20): 1 - 2/(e^{2x}+1).
__device__ __forceinline__ float tanh_b(float x){
    float e = __expf(2.0f * x);
    return fmaf(-2.0f, __builtin_amdgcn_rcpf(e + 1.0f), 1.0f);
}
__device__ __forceinline__ void barrier_lgkm(){
    asm volatile("s_waitcnt lgkmcnt(0)\n\ts_barrier" ::: "memory");
}

// ---------------------------------------------------------------------------
// K1 (fused): blocks < 512: EW[v,d] = embed[v] @ W_ih + b_h  (fp32 exact).
// blocks 512..1023: Wab/Uab transpose+convert (bf16).
// ---------------------------------------------------------------------------
__global__ __launch_bounds__(256) void k_ew_cvt(const float* __restrict__ embed,
                                                const float* __restrict__ W_ih,
                                                const float* __restrict__ b_h,
                                                float* __restrict__ EW,
                                                const float* __restrict__ W_att,
                                                const float* __restrict__ U_att,
                                                u16* __restrict__ Wab){
    __shared__ float er[E_];
    int blk = blockIdx.x;
    int tid = threadIdx.x;
    if (blk < V_){
        if (tid < E_) er[tid] = embed[blk*E_ + tid];
        __syncthreads();
        float acc = b_h[tid];
        #pragma unroll 4
        for (int e = 0; e < E_; ++e) acc += er[e] * W_ih[e*D_ + tid];
        EW[blk*D_ + tid] = acc;
    } else {
        int i = (blk - V_) * 256 + tid;       // 0..131071
        if (i < 65536){
            int n = i >> 8, k = i & 255;
            Wab[i] = f2bf(W_att[k*D_ + n]);
        } else {
            int j = i - 65536;
            int n = j >> 8, k = j & 255;
            Wab[i] = f2bf(U_att[k*D_ + n]);   // Uab contiguous after Wab
        }
    }
}

// ---------------------------------------------------------------------------
// K1b: XP[t*64+b][d] = EW[x[b][t]][d]  (fp32 streaming layout for k_rnn).
// ---------------------------------------------------------------------------
__global__ __launch_bounds__(256) void k_gather(const int* __restrict__ x,
                                                const float* __restrict__ EW,
                                                float* __restrict__ XP){
    int m = blockIdx.x * 4 + (threadIdx.x >> 6);   // row index t*64+b
    int lane = threadIdx.x & 63;
    int b = m & 63, t = m >> 6;
    int v = x[b*T_ + t];
    float4 val = *(const float4*)&EW[v*D_ + lane*4];
    *(float4*)&XP[(size_t)m*D_ + lane*4] = val;
}

// ---------------------------------------------------------------------------
// K1c: fcWb[n*512+k] = bf16(fc_W[k*512+n]) — runs AFTER gather, writes over
// the dead EW region.
// ---------------------------------------------------------------------------
__global__ __launch_bounds__(256) void k_cvt_fc(const float* __restrict__ fc_W,
                                                u16* __restrict__ fcWb){
    int j = blockIdx.x * 256 + threadIdx.x;   // 0..262143
    int n = j >> 9, k = j & 511;
    fcWb[j] = f2bf(fc_W[k*V_ + n]);
}

// ===========================================================================
// MEGAKERNEL: blocks 0..15 = rnn chain (proven round-5/7/10 code) publishing
// per-8-step chunks; blocks 16..255 = persistent workers doing PQ tiles then
// energy tiles from an atomic work queue, spin-waiting on progress flags.
// Deadlock-free: all 256 blocks co-resident (8 waves, ~37KB LDS -> 4 blk/CU
// capacity); rnn never waits on workers; items claimed in dependency order.
// flags[0..63]  = rnn 8-step chunks (target 16 blocks each)
// flags[64..79] = PQ 32-t chunks    (target 256 tiles each)
// flags[95]     = work counter
// ===========================================================================

__device__ void rnn_block(const float* __restrict__ XP,
                          const float* __restrict__ W_hh,
                          u16* __restrict__ HC,
                          u32* __restrict__ flags,
                          char* smem, int tid){
    u16 (*hf)[4][272] = (u16 (*)[4][272])smem;   // [2][4][272] fp16 h dbuf
    int lane = tid & 63;
    int w    = tid >> 6;
    int col  = lane & 15;
    int colA = col & 3;
    int quad = lane >> 4;
    int bb0  = blockIdx.x * 4;

    f16x8 bfh[2][8];
    #pragma unroll
    for (int nt = 0; nt < 2; ++nt){
        int n = w*32 + nt*16 + col;
        #pragma unroll
        for (int ks = 0; ks < 8; ++ks){
            f16x8 th;
            #pragma unroll
            for (int j = 0; j < 8; ++j){
                int k = ks*32 + quad*8 + j;
                th[j] = (_Float16)W_hh[k*D_ + n];
            }
            bfh[nt][ks] = th;
        }
    }
    for (int i = tid; i < 2*4*272; i += 512) (&hf[0][0][0])[i] = 0;

    const float* p  = XP + (size_t)bb0*D_ + w*32 + col;
    u16*         hc = HC + (size_t)bb0*D2_ + w*32 + col;

    float ewv[2][4];
    #pragma unroll
    for (int nt = 0; nt < 2; ++nt)
        #pragma unroll
        for (int r = 0; r < 4; ++r)
            ewv[nt][r] = p[r*D_ + nt*16];
    p += (size_t)B_*D_;
    __syncthreads();

    for (int t = 0; t < T_; ++t){
        int rb = t & 1, wb = rb ^ 1;
        f32x4 acc[2];
        #pragma unroll
        for (int nt = 0; nt < 2; ++nt)
            #pragma unroll
            for (int r = 0; r < 4; ++r) acc[nt][r] = ewv[nt][r];

        f16x8 ah[8];
        #pragma unroll
        for (int ks = 0; ks < 8; ++ks)
            ah[ks] = *(const f16x8*)&hf[rb][colA][ks*32 + quad*8];

        if (t + 1 < T_){
            #pragma unroll
            for (int nt = 0; nt < 2; ++nt)
                #pragma unroll
                for (int r = 0; r < 4; ++r)
                    ewv[nt][r] = p[r*D_ + nt*16];
        }
        p += (size_t)B_*D_;

        #pragma unroll
        for (int ks = 0; ks < 8; ++ks){
            acc[0] = __builtin_amdgcn_mfma_f32_16x16x32_f16(ah[ks], bfh[0][ks], acc[0], 0, 0, 0);
            acc[1] = __builtin_amdgcn_mfma_f32_16x16x32_f16(ah[ks], bfh[1][ks], acc[1], 0, 0, 0);
        }

        #pragma unroll
        for (int nt = 0; nt < 2; ++nt){
            f32x4 s = acc[nt];
            float v = (quad & 2) ? ((quad & 1) ? s[3] : s[2])
                                 : ((quad & 1) ? s[1] : s[0]);
            float h  = tanh_b(v);
            int n    = w*32 + nt*16 + col;
            hf[wb][quad][n]      = f2h(h);
            hc[quad*D2_ + nt*16] = f2bf(h);
        }
        hc += (size_t)B_*D2_;

        if ((t & 7) == 7){
            // publish chunk t>>3: drain all HC stores, then device-scope release
            asm volatile("s_waitcnt vmcnt(0) lgkmcnt(0)" ::: "memory");
            __syncthreads();
            if (tid == 0)
                __hip_atomic_fetch_add(&flags[t >> 3], 1u,
                                       __ATOMIC_RELEASE, __HIP_MEMORY_SCOPE_AGENT);
        } else {
            barrier_lgkm();
        }
    }
}

// PQ tile: one t (64 HC rows) x 64 cols of [Wab|Uab], K=256. 512 threads,
// 8 waves as 2M x 4N. Proven stride-88 LDS, proven fragment mapping.
__device__ void pq_tile(int t, int nt, const u16* __restrict__ HC,
                        const u16* __restrict__ Wab,
                        u16* __restrict__ EP, u16* __restrict__ EQ,
                        char* smem, int tid){
    u16 (*As)[88] = (u16 (*)[88])smem;
    u16 (*Ws)[88] = (u16 (*)[88])(smem + 64*88*2);
    int lane = tid & 63;
    int w  = tid >> 6;
    int wm = w >> 2, wn = w & 3;
    int col = lane & 15, quad = lane >> 4;
    int m0 = t * 64, n0 = nt * 64;
    int r  = tid >> 3, c8 = (tid & 7) * 8;

    f32x4 acc[2];
    #pragma unroll
    for (int mt = 0; mt < 2; ++mt)
        #pragma unroll
        for (int rr = 0; rr < 4; ++rr) acc[mt][rr] = 0.0f;

    for (int kk = 0; kk < D_; kk += 64){
        *(s16x8*)&As[r][c8] = *(const s16x8*)&HC [(size_t)(m0 + r)*D2_ + kk + c8];
        *(s16x8*)&Ws[r][c8] = *(const s16x8*)&Wab[(size_t)(n0 + r)*D_  + kk + c8];
        barrier_lgkm();
        #pragma unroll
        for (int ks = 0; ks < 2; ++ks){
            s16x8 b = *(const s16x8*)&Ws[wn*16 + col][ks*32 + quad*8];
            #pragma unroll
            for (int mt = 0; mt < 2; ++mt){
                s16x8 a = *(const s16x8*)&As[wm*32 + mt*16 + col][ks*32 + quad*8];
                acc[mt] = __builtin_amdgcn_mfma_f32_16x16x32_bf16(a, b, acc[mt], 0, 0, 0);
            }
        }
        barrier_lgkm();
    }
    int n = n0 + wn*16 + col;
    u16* dst = (n < D_) ? EP : EQ;
    int nn = n & 255;
    #pragma unroll
    for (int mt = 0; mt < 2; ++mt)
        #pragma unroll
        for (int rr = 0; rr < 4; ++rr){
            int m = m0 + wm*32 + mt*16 + quad*4 + rr;
            dst[(size_t)m*D_ + nn] = f2bf(__expf(2.0f * acc[mt][rr]));
        }
}

// Energy tile: (b, tt, pt), 32 t x 32 tp over d=256. 512 threads: tg=tid>>4
// owns t=tt*32+tg, dg=tid&15 owns 16 d. Proven padded-eps layout + grouped
// 4-per-rcp math; 4-level 16-lane shfl reduction.
__device__ void energy_tile(int b, int tt, int pt,
                            const u16* __restrict__ EP, const u16* __restrict__ EQ,
                            const float* __restrict__ v_attn,
                            u16* __restrict__ Wx, char* smem, int tid){
    float (*eps)[288] = (float (*)[288])smem;   // 32*288*4 = 36864 B
    int tg = tid >> 4, dg = tid & 15;
    int d0 = dg * 16;
    int t  = tt*32 + tg;

    #pragma unroll
    for (int i = 0; i < 4; ++i){
        int idx = tid + i*512;            // 0..2047, 4 bf16 each
        int row = idx >> 6;
        int c4  = (idx & 63) * 4;
        int pc  = c4 + ((c4 >> 5) << 2);
        u16x4 v4 = *(const u16x4*)&EP[((size_t)((pt*32 + row)*B_ + b))*D_ + c4];
        *(float4*)&eps[row][pc] = make_float4(bf2f(v4.x), bf2f(v4.y), bf2f(v4.z), bf2f(v4.w));
    }

    float eq[16], vm2[16], sv = 0.0f;
    #pragma unroll
    for (int i = 0; i < 4; ++i){
        u16x4 v4 = *(const u16x4*)&EQ[((size_t)(t*B_ + b))*D_ + d0 + i*4];
        eq[i*4+0] = bf2f(v4.x); eq[i*4+1] = bf2f(v4.y);
        eq[i*4+2] = bf2f(v4.z); eq[i*4+3] = bf2f(v4.w);
    }
    #pragma unroll
    for (int i = 0; i < 16; ++i){
        float v = v_attn[d0 + i];
        sv += v;
        vm2[i] = -2.0f * v;
    }
    int po[4];
    #pragma unroll
    for (int g = 0; g < 4; ++g){ int c = d0 + 4*g; po[g] = c + ((c >> 5) << 2); }
    barrier_lgkm();

    for (int tpl = 0; tpl < 32; ++tpl){
        int tp = pt*32 + tpl;
        float acc = sv;
        #pragma unroll
        for (int g = 0; g < 4; ++g){
            float4 ep = *(const float4*)&eps[tpl][po[g]];
            float da = fmaf(ep.x, eq[4*g+0], 1.0f);
            float db = fmaf(ep.y, eq[4*g+1], 1.0f);
            float dc = fmaf(ep.z, eq[4*g+2], 1.0f);
            float dd = fmaf(ep.w, eq[4*g+3], 1.0f);
            float dab = da * db;
            float dcd = dc * dd;
            float nab = fmaf(vm2[4*g+1], da, vm2[4*g+0] * db);
            float ncd = fmaf(vm2[4*g+3], dc, vm2[4*g+2] * dd);
            float num = fmaf(ncd, dab, nab * dcd);
            acc = fmaf(num, __builtin_amdgcn_rcpf(dab * dcd), acc);
        }
        acc += __shfl_xor(acc, 1);
        acc += __shfl_xor(acc, 2);
        acc += __shfl_xor(acc, 4);
        acc += __shfl_xor(acc, 8);
        if (dg == 0 && tp < t)
            Wx[((size_t)(b*T_ + t))*T_ + tp] = f2bf(__expf(acc));
    }
}

__device__ void worker_loop(const u16* __restrict__ HC,
                            const u16* __restrict__ Wab,
                            u16* __restrict__ EP, u16* __restrict__ EQ,
                            const float* __restrict__ v_attn,
                            u16* __restrict__ Wx,
                            u32* __restrict__ flags,
                            char* smem, int tid){
    volatile int* s_item = (volatile int*)(smem + 36864);
    for (;;){
        __syncthreads();   // quiesce smem (incl. s_item) from prior iteration
        if (tid == 0)
            *s_item = (int)__hip_atomic_fetch_add(&flags[95], 1u,
                          __ATOMIC_RELAXED, __HIP_MEMORY_SCOPE_AGENT);
        __syncthreads();
        int item = *s_item;
        if (item >= NITEMS) return;

        if (item < NPQ){
            int t  = item >> 3, nt = item & 7;
            if (tid == 0){
                while (__hip_atomic_load(&flags[t >> 3], __ATOMIC_ACQUIRE,
                                         __HIP_MEMORY_SCOPE_AGENT) < 16u)
                    __builtin_amdgcn_s_sleep(8);
            }
            __syncthreads();
            pq_tile(t, nt, HC, Wab, EP, EQ, smem, tid);
            asm volatile("s_waitcnt vmcnt(0)" ::: "memory");
            __syncthreads();
            if (tid == 0)
                __hip_atomic_fetch_add(&flags[64 + (t >> 5)], 1u,
                                       __ATOMIC_RELEASE, __HIP_MEMORY_SCOPE_AGENT);
        } else {
            int e  = item - NPQ;
            int pi = e >> 6, b = e & 63;
            int tt = 0;
            while ((tt+1)*(tt+2)/2 <= pi) ++tt;
            int pt = pi - tt*(tt+1)/2;
            if (tid == 0){
                while (__hip_atomic_load(&flags[64 + tt], __ATOMIC_ACQUIRE,
                                         __HIP_MEMORY_SCOPE_AGENT) < 256u)
                    __builtin_amdgcn_s_sleep(8);
                while (__hip_atomic_load(&flags[64 + pt], __ATOMIC_ACQUIRE,
                                         __HIP_MEMORY_SCOPE_AGENT) < 256u)
                    __builtin_amdgcn_s_sleep(8);
            }
            __syncthreads();
            energy_tile(b, tt, pt, EP, EQ, v_attn, Wx, smem, tid);
        }
    }
}

__global__ __launch_bounds__(512, 2) void k_mega(const float* __restrict__ XP,
                                                 const float* __restrict__ W_hh,
                                                 u16* __restrict__ HC,
                                                 const u16* __restrict__ Wab,
                                                 const float* __restrict__ v_attn,
                                                 u16* __restrict__ EP,
                                                 u16* __restrict__ EQ,
                                                 u16* __restrict__ Wx,
                                                 u32* __restrict__ flags){
    __shared__ __align__(16) char smem[36880];
    int tid = threadIdx.x;
    if (blockIdx.x < 16)
        rnn_block(XP, W_hh, HC, flags, smem, tid);
    worker_loop(HC, Wab, EP, EQ, v_attn, Wx, flags, smem, tid);
}

// ---------------------------------------------------------------------------
// K6: ctx[b][t][d] = (sum_t' Wx[b][t][t'] * h[t'][d]) / l[b][t]; t=0 -> h[0].
// TRIANGULAR K-loop; diagonal tile masked (unwritten Wx never read); row sums
// from staged post-mask values. Proven rounds 8-10.
// ---------------------------------------------------------------------------
__global__ __launch_bounds__(256) void k_ctx(const u16* __restrict__ Wx,
                                             u16* __restrict__ HC){
    __shared__ u16 As[64][88];
    __shared__ u16 Ws[64][88];
    __shared__ float rs[64];
    int tid  = threadIdx.x;
    int lane = tid & 63;
    int w    = tid >> 6;
    int col  = lane & 15;
    int quad = lane >> 4;
    int b    = blockIdx.y;
    int m0   = (blockIdx.x >> 2) * 64;   // t tile
    int n0   = (blockIdx.x & 3) * 64;    // d tile

    const u16* A = Wx + (size_t)b * T_ * T_;

    int r0 = tid >> 3;
    int c8 = (tid & 7) * 8;
    float rsum0 = 0.0f, rsum1 = 0.0f;

    f32x4 acc[4];
    #pragma unroll
    for (int nt = 0; nt < 4; ++nt)
        #pragma unroll
        for (int r = 0; r < 4; ++r) acc[nt][r] = 0.0f;

    int kmax = m0 + 64;
    for (int kk = 0; kk < kmax; kk += 64){
        bool diag = (kk == m0);
        #pragma unroll
        for (int i = 0; i < 2; ++i){
            int r = r0 + i*32;
            s16x8 v = *(const s16x8*)&A[(size_t)(m0 + r)*T_ + kk + c8];
            if (diag){
                #pragma unroll
                for (int j = 0; j < 8; ++j)
                    if (c8 + j >= r) v[j] = 0;
            }
            *(s16x8*)&As[r][c8] = v;
            float s = 0.0f;
            #pragma unroll
            for (int j = 0; j < 8; ++j) s += bf2f((u16)v[j]);
            if (i == 0) rsum0 += s; else rsum1 += s;
        }
        #pragma unroll
        for (int i = 0; i < 8; ++i){
            int idx = tid + i*256;
            int k   = idx >> 5;
            int n2  = (idx & 31) * 2;
            u16x2 v2 = *(const u16x2*)&HC[((size_t)((kk + k)*B_ + b))*D2_ + n0 + n2];
            Ws[n2][k]   = v2.x;
            Ws[n2+1][k] = v2.y;
        }
        barrier_lgkm();
        #pragma unroll
        for (int ks = 0; ks < 2; ++ks){
            s16x8 a = *(const s16x8*)&As[w*16 + col][ks*32 + quad*8];
            #pragma unroll
            for (int nt = 0; nt < 4; ++nt){
                s16x8 bb = *(const s16x8*)&Ws[nt*16 + col][ks*32 + quad*8];
                acc[nt] = __builtin_amdgcn_mfma_f32_16x16x32_bf16(a, bb, acc[nt], 0, 0, 0);
            }
        }
        barrier_lgkm();
    }

    rsum0 += __shfl_xor(rsum0, 1); rsum0 += __shfl_xor(rsum0, 2); rsum0 += __shfl_xor(rsum0, 4);
    rsum1 += __shfl_xor(rsum1, 1); rsum1 += __shfl_xor(rsum1, 2); rsum1 += __shfl_xor(rsum1, 4);
    if ((tid & 7) == 0){ rs[r0] = rsum0; rs[r0 + 32] = rsum1; }
    barrier_lgkm();

    float linv[4];
    #pragma unroll
    for (int r = 0; r < 4; ++r){
        int rr = w*16 + quad*4 + r;
        float lv = (m0 + rr > 0) ? rs[rr] : 1.0f;
        linv[r] = 1.0f / lv;
    }
    #pragma unroll
    for (int nt = 0; nt < 4; ++nt){
        int n = n0 + nt*16 + col;
        #pragma unroll
        for (int r = 0; r < 4; ++r){
            int t = m0 + w*16 + quad*4 + r;
            u16 ov;
            if (t == 0) ov = HC[(size_t)b*D2_ + n];
            else        ov = f2bf(acc[nt][r] * linv[r]);
            HC[((size_t)(t*B_ + b))*D2_ + D_ + n] = ov;
        }
    }
}

// ---------------------------------------------------------------------------
// K4b: final fc layer, 128x128x64 tile (512 thr, 8 waves as 2Mx4N).
// ---------------------------------------------------------------------------
__global__ __launch_bounds__(512) void k_fc(const u16* __restrict__ A,
                                            const u16* __restrict__ Wb,
                                            const float* __restrict__ bias,
                                            float* __restrict__ out){
    __shared__ u16 As[128][88];
    __shared__ u16 Ws[128][88];
    int tid  = threadIdx.x;
    int lane = tid & 63;
    int w    = tid >> 6;
    int wm   = w >> 2;
    int wn   = w & 3;
    int col  = lane & 15;
    int quad = lane >> 4;
    int m0   = blockIdx.x * 128;
    int n0   = blockIdx.y * 128;

    f32x4 acc[4][2];
    #pragma unroll
    for (int mt = 0; mt < 4; ++mt)
        #pragma unroll
        for (int nt = 0; nt < 2; ++nt)
            #pragma unroll
            for (int r = 0; r < 4; ++r) acc[mt][nt][r] = 0.0f;

    for (int kk = 0; kk < D2_; kk += 64){
        #pragma unroll
        for (int i = 0; i < 2; ++i){
            int idx = tid + i*512;
            int r   = idx >> 3;
            int c8  = (idx & 7) * 8;
            *(s16x8*)&As[r][c8] = *(const s16x8*)&A [(size_t)(m0 + r)*D2_ + kk + c8];
            *(s16x8*)&Ws[r][c8] = *(const s16x8*)&Wb[(size_t)(n0 + r)*D2_ + kk + c8];
        }
        barrier_lgkm();
        #pragma unroll
        for (int ks = 0; ks < 2; ++ks){
            s16x8 b0 = *(const s16x8*)&Ws[wn*32 +      col][ks*32 + quad*8];
            s16x8 b1 = *(const s16x8*)&Ws[wn*32 + 16 + col][ks*32 + quad*8];
            #pragma unroll
            for (int mt = 0; mt < 4; ++mt){
                s16x8 a = *(const s16x8*)&As[wm*64 + mt*16 + col][ks*32 + quad*8];
                acc[mt][0] = __builtin_amdgcn_mfma_f32_16x16x32_bf16(a, b0, acc[mt][0], 0, 0, 0);
                acc[mt][1] = __builtin_amdgcn_mfma_f32_16x16x32_bf16(a, b1, acc[mt][1], 0, 0, 0);
            }
        }
        barrier_lgkm();
    }
    #pragma unroll
    for (int nt = 0; nt < 2; ++nt){
        int n = n0 + wn*32 + nt*16 + col;
        float bv = bias[n];
        #pragma unroll
        for (int mt = 0; mt < 4; ++mt){
            #pragma unroll
            for (int r = 0; r < 4; ++r){
                int m = m0 + wm*64 + mt*16 + quad*4 + r;
                int b = m & 63, t = m >> 6;
                out[(size_t)(b*T_ + t)*V_ + n] = acc[mt][nt][r] + bv;
            }
        }
    }
}

// ---------------------------------------------------------------------------
extern "C" void kernel_launch(void* const* d_in, const int* in_sizes, int n_in,
                              void* d_out, int out_size, void* d_ws, size_t ws_size,
                              hipStream_t stream){
    const int*   x     = (const int*)d_in[0];
    const float* embed = (const float*)d_in[1];
    const float* W_ih  = (const float*)d_in[2];
    const float* W_hh  = (const float*)d_in[3];
    const float* b_h   = (const float*)d_in[4];
    const float* W_att = (const float*)d_in[5];
    const float* U_att = (const float*)d_in[6];
    const float* v_att = (const float*)d_in[7];
    const float* fc_W  = (const float*)d_in[8];
    const float* fc_b  = (const float*)d_in[9];

    char* ws = (char*)d_ws;
    float* EW   = (float*)ws;                       // 512 KB (dead after gather)
    u16*   fcWb = (u16*)ws;                         // 512 KB, ALIASES EW (k_cvt_fc after gather)
    u16*   Wab  = (u16*)(ws + 524288);              // 256 KB bf16 [W_att^T | U_att^T]
    u16*   HC   = (u16*)(ws + 786432);              // 32 MB  [h|ctx] bf16
    float* XP   = (float*)(ws + 34340864);          // 32 MB  fp32 x-projection
    u32*   flags= (u32*)(ws + 67895296);            // 512 B  sync flags (<= proven ws watermark)

    char* dob = (char*)d_out;
    u16*   Wx   = (u16*)dob;                        // 33.5 MB  (d_out lower half)
    u16*   EP   = (u16*)(dob + 33554432);           // 16 MB    (d_out upper half)
    u16*   EQ   = (u16*)(dob + 50331648);           // 16 MB

    (void)hipMemsetAsync(flags, 0, 512, stream);

    k_ew_cvt<<<dim3(1024),     dim3(256), 0, stream>>>(embed, W_ih, b_h, EW,
                                                       W_att, U_att, Wab);
    k_gather<<<dim3(T_*B_/4),  dim3(256), 0, stream>>>(x, EW, XP);
    k_cvt_fc<<<dim3(1024),     dim3(256), 0, stream>>>(fc_W, fcWb);
    k_mega  <<<dim3(256),      dim3(512), 0, stream>>>(XP, W_hh, HC, Wab, v_att,
                                                       EP, EQ, Wx, flags);
    k_ctx   <<<dim3(32, B_),   dim3(256), 0, stream>>>(Wx, HC);
    k_fc    <<<dim3(256, 4),   dim3(512), 0, stream>>>(HC, fcWb, fc_b, (float*)d_out);
}